// Round 1
// baseline (815.037 us; speedup 1.0000x reference)
//
#include <hip/hip_runtime.h>
#include <stdint.h>

// Problem constants
#define N_B 8
#define F_T 16
#define S_T 196
#define D_M 1024
#define H_N 8
#define HD  128
#define L_T 3137              // 1 + F*S
#define M_R (N_B * L_T)       // 25096 real rows
#define M_P 25216             // 197*128 padded rows

typedef __attribute__((ext_vector_type(8))) short bf16x8;
typedef __attribute__((ext_vector_type(4))) float f32x4;

__device__ __forceinline__ float b2f(unsigned int u) {
  union { unsigned int i; float f; } x; x.i = u << 16; return x.f;
}
__device__ __forceinline__ unsigned short f2b(float f) {
  union { float f; unsigned int i; } x; x.f = f;
  unsigned int r = x.i + 0x7fffu + ((x.i >> 16) & 1u);  // RNE
  return (unsigned short)(r >> 16);
}

// ---------------- convert fp32 x -> bf16, zero-pad rows M_R..M_P ----------------
__global__ __launch_bounds__(256) void convert_pad(const float* __restrict__ x,
                                                   unsigned short* __restrict__ xb,
                                                   int nreal) {
  int i = (blockIdx.x * 256 + threadIdx.x) * 4;
  float4 v;
  if (i < nreal) v = *(const float4*)(x + i);
  else { v.x = 0.f; v.y = 0.f; v.z = 0.f; v.w = 0.f; }
  ushort4 o;
  o.x = f2b(v.x); o.y = f2b(v.y); o.z = f2b(v.z); o.w = f2b(v.w);
  *(ushort4*)(xb + i) = o;
}

// ---------------- transpose 5 weights: W[k][n] fp32 -> Wt[n][k] bf16 ----------------
struct WP { const float* s[5]; unsigned short* d[5]; };
__global__ __launch_bounds__(256) void transpose5(WP p) {
  __shared__ float t[32][33];
  const int w = blockIdx.z;
  const float* W = p.s[w];
  unsigned short* Wt = p.d[w];
  const int tx = threadIdx.x, ty = threadIdx.y;    // 32 x 8
  const int n0 = blockIdx.x * 32, k0 = blockIdx.y * 32;
#pragma unroll
  for (int i = 0; i < 4; i++)
    t[ty + i * 8][tx] = W[(size_t)(k0 + ty + i * 8) * D_M + n0 + tx];
  __syncthreads();
#pragma unroll
  for (int i = 0; i < 4; i++)
    Wt[(size_t)(n0 + ty + i * 8) * D_M + k0 + tx] = f2b(t[tx][ty + i * 8]);
}

// ---------------- GEMM: C[M_P x 1024] = A[M_P x 1024] * Wt^T, m97-style ----------------
__device__ __forceinline__ void async16(const unsigned short* g, unsigned short* l) {
  __builtin_amdgcn_global_load_lds((const __attribute__((address_space(1))) void*)g,
                                   (__attribute__((address_space(3))) void*)l, 16, 0, 0);
}

// MODE 0: out bf16, no bias. MODE 1: out bf16 + bias. MODE 2: out fp32 + bias, row<Mreal guard.
template <int MODE>
__global__ __launch_bounds__(256) void gemm_bt(const unsigned short* __restrict__ A,
                                               const unsigned short* __restrict__ Bt,
                                               const float* __restrict__ bias,
                                               void* __restrict__ Cout, int Mreal) {
  __shared__ __align__(16) unsigned short As[128 * 32];  // [m][k], rows of 64B
  __shared__ __align__(16) unsigned short Bs[128 * 32];  // [n][k]
  const int tid = threadIdx.x;
  const int lane = tid & 63;
  const int wv = tid >> 6;
  const int wm = wv >> 1, wn = wv & 1;
  const int rowBase = blockIdx.y * 128, colBase = blockIdx.x * 128;

  // staging: wave wv loads LDS chunks {2wv, 2wv+1} (1KB each) of A and B tiles
  const int c0 = 2 * wv, c1 = c0 + 1;
  const int srow = lane >> 2;           // row within 16-row chunk
  const int sk = (lane & 3) * 8;        // k element offset (16B granules)
  const unsigned short* gA0 = A + (size_t)(rowBase + c0 * 16 + srow) * 1024 + sk;
  const unsigned short* gA1 = A + (size_t)(rowBase + c1 * 16 + srow) * 1024 + sk;
  const unsigned short* gB0 = Bt + (size_t)(colBase + c0 * 16 + srow) * 1024 + sk;
  const unsigned short* gB1 = Bt + (size_t)(colBase + c1 * 16 + srow) * 1024 + sk;
  unsigned short* lA0 = As + c0 * 512;
  unsigned short* lA1 = As + c1 * 512;
  unsigned short* lB0 = Bs + c0 * 512;
  unsigned short* lB1 = Bs + c1 * 512;

  f32x4 acc[4][4] = {};

  // fragment read addresses: A[m=lane&15][k=(lane>>4)*8+j]  (m120-verified layout)
  const int mf = lane & 15, kg = lane >> 4;
  const unsigned short* Ar = As + (wm * 64 + mf) * 32 + kg * 8;
  const unsigned short* Br = Bs + (wn * 64 + mf) * 32 + kg * 8;

  for (int kt = 0; kt < 1024; kt += 32) {
    __syncthreads();                 // previous tile's ds_reads done
    async16(gA0 + kt, lA0);
    async16(gA1 + kt, lA1);
    async16(gB0 + kt, lB0);
    async16(gB1 + kt, lB1);
    __syncthreads();                 // drains vmcnt(0) -> LDS ready
    bf16x8 av[4], bv[4];
#pragma unroll
    for (int i = 0; i < 4; i++) av[i] = *(const bf16x8*)(Ar + i * 16 * 32);
#pragma unroll
    for (int j = 0; j < 4; j++) bv[j] = *(const bf16x8*)(Br + j * 16 * 32);
#pragma unroll
    for (int i = 0; i < 4; i++)
#pragma unroll
      for (int j = 0; j < 4; j++)
        acc[i][j] = __builtin_amdgcn_mfma_f32_16x16x32_bf16(av[i], bv[j], acc[i][j], 0, 0, 0);
  }

  // epilogue: C/D layout col=lane&15, row=(lane>>4)*4+reg (m89-verified)
  const int r0 = (lane >> 4) * 4;
  const int cc = lane & 15;
#pragma unroll
  for (int j = 0; j < 4; j++) {
    const int col = colBase + wn * 64 + j * 16 + cc;
    const float bval = (MODE >= 1) ? bias[col] : 0.f;
#pragma unroll
    for (int i = 0; i < 4; i++) {
#pragma unroll
      for (int r = 0; r < 4; r++) {
        const int row = rowBase + wm * 64 + i * 16 + r0 + r;
        const float val = acc[i][j][r] + bval;
        if (MODE == 2) {
          if (row < Mreal) ((float*)Cout)[(size_t)row * 1024 + col] = val;
        } else {
          ((unsigned short*)Cout)[(size_t)row * 1024 + col] = f2b(val);
        }
      }
    }
  }
}

// ---------------- LayerNorm over rows of 1024, bf16 in/out ----------------
// src0 != nullptr: rows with (row % L_T)==0 read from src0 instead (feat_q passthrough).
__global__ __launch_bounds__(256) void ln_kernel(const unsigned short* __restrict__ src,
                                                 const unsigned short* __restrict__ src0,
                                                 const float* __restrict__ g,
                                                 const float* __restrict__ beta,
                                                 unsigned short* __restrict__ out, int Mreal) {
  const int row = blockIdx.x, tid = threadIdx.x;
  unsigned short* op = out + (size_t)row * 1024 + tid * 4;
  if (row >= Mreal) {                       // zero the pad rows
    ushort4 z; z.x = 0; z.y = 0; z.z = 0; z.w = 0;
    *(ushort4*)op = z;
    return;
  }
  const unsigned short* s = src;
  if (src0 != nullptr && (row % L_T) == 0) s = src0;
  const unsigned short* ip = s + (size_t)row * 1024 + tid * 4;
  uint2 raw = *(const uint2*)ip;
  float x0 = b2f(raw.x & 0xffffu), x1 = b2f(raw.x >> 16);
  float x2 = b2f(raw.y & 0xffffu), x3 = b2f(raw.y >> 16);
  float sum = x0 + x1 + x2 + x3;
  float sq = x0 * x0 + x1 * x1 + x2 * x2 + x3 * x3;
#pragma unroll
  for (int off = 32; off > 0; off >>= 1) {
    sum += __shfl_down(sum, off);
    sq += __shfl_down(sq, off);
  }
  __shared__ float red[8];
  if ((tid & 63) == 0) { red[tid >> 6] = sum; red[4 + (tid >> 6)] = sq; }
  __syncthreads();
  const float ts = red[0] + red[1] + red[2] + red[3];
  const float tq = red[4] + red[5] + red[6] + red[7];
  const float mean = ts * (1.f / 1024.f);
  const float var = tq * (1.f / 1024.f) - mean * mean;
  const float rstd = rsqrtf(var + 1e-5f);
  const float4 gv = *(const float4*)(g + tid * 4);
  const float4 bv = *(const float4*)(beta + tid * 4);
  ushort4 o;
  o.x = f2b((x0 - mean) * rstd * gv.x + bv.x);
  o.y = f2b((x1 - mean) * rstd * gv.y + bv.y);
  o.z = f2b((x2 - mean) * rstd * gv.z + bv.z);
  o.w = f2b((x3 - mean) * rstd * gv.w + bv.w);
  *(ushort4*)op = o;
}

// ---------------- Attention ----------------
// type 1 (temporal): block = (hb, s), 16 queries x 17 keys.
// type 0 (spatial):  block = (hb, f, qchunk), 16 queries x 197 keys.
// NOTE: jnp.tile(feat_k,(S,1,1)) means batch i uses feat head (i % 64), not its own head!
__global__ __launch_bounds__(256) void attn_kernel(const unsigned short* __restrict__ q,
                                                   const unsigned short* __restrict__ k,
                                                   const unsigned short* __restrict__ v,
                                                   unsigned short* __restrict__ out,
                                                   const int* __restrict__ att_type) {
  __shared__ float qs[16][132];   // padded: 4-word row-stride offset breaks bank aliasing
  __shared__ float sc[16][212];
  const int tid = threadIdx.x;
  const int bid = blockIdx.x;
  const int at = att_type[0];

  int nk, nqv, qbase, qstride, kbase, kstride, frow, fcol, hcol;
  if (at == 1) {
    if (bid >= 64 * S_T) return;
    const int hb = bid / S_T;
    const int s = bid - hb * S_T;
    const int n = hb >> 3, h = hb & 7;
    const int fi = bid & 63;                // (hb*S + s) % nh — tile() modular indexing
    frow = (fi >> 3) * L_T; fcol = (fi & 7) * HD;
    qbase = n * L_T + 1 + s; qstride = S_T;
    kbase = qbase; kstride = S_T;
    nk = F_T + 1; nqv = 16; hcol = h * HD;
  } else {
    const int hb = bid / 208;
    const int rem = bid - hb * 208;
    const int f = rem / 13, qc = rem - f * 13;
    const int n = hb >> 3, h = hb & 7;
    const int fi = (hb * F_T + f) & 63;
    frow = (fi >> 3) * L_T; fcol = (fi & 7) * HD;
    kbase = n * L_T + 1 + f * S_T; kstride = 1;
    qbase = kbase + qc * 16; qstride = 1;
    nk = S_T + 1; nqv = (qc == 12) ? 4 : 16; hcol = h * HD;
  }

  // stage q chunk (16 x 128) into LDS as fp32
  {
    const int i = tid >> 4, db = (tid & 15) * 8;
    float* dst = &qs[i][db];
    if (i < nqv) {
      const unsigned short* qp = q + (size_t)(qbase + i * qstride) * 1024 + hcol + db;
      uint4 r = *(const uint4*)qp;
      dst[0] = b2f(r.x & 0xffffu); dst[1] = b2f(r.x >> 16);
      dst[2] = b2f(r.y & 0xffffu); dst[3] = b2f(r.y >> 16);
      dst[4] = b2f(r.z & 0xffffu); dst[5] = b2f(r.z >> 16);
      dst[6] = b2f(r.w & 0xffffu); dst[7] = b2f(r.w >> 16);
    } else {
#pragma unroll
      for (int u = 0; u < 8; u++) dst[u] = 0.f;
    }
  }
  __syncthreads();

  // scores: s[i][j] = (q_i . k_j) / sqrt(128)
  const int nslot = 16 * nk;
  for (int slot = tid; slot < nslot; slot += 256) {
    const int i = slot / nk, j = slot - i * nk;
    const unsigned short* kp = (j == 0)
        ? (k + (size_t)frow * 1024 + fcol)
        : (k + (size_t)(kbase + (j - 1) * kstride) * 1024 + hcol);
    float acc = 0.f;
#pragma unroll 4
    for (int d = 0; d < 128; d += 8) {
      uint4 r = *(const uint4*)(kp + d);
      acc += qs[i][d + 0] * b2f(r.x & 0xffffu);
      acc += qs[i][d + 1] * b2f(r.x >> 16);
      acc += qs[i][d + 2] * b2f(r.y & 0xffffu);
      acc += qs[i][d + 3] * b2f(r.y >> 16);
      acc += qs[i][d + 4] * b2f(r.z & 0xffffu);
      acc += qs[i][d + 5] * b2f(r.z >> 16);
      acc += qs[i][d + 6] * b2f(r.w & 0xffffu);
      acc += qs[i][d + 7] * b2f(r.w >> 16);
    }
    sc[i][j] = acc * 0.08838834764831845f;   // 1/sqrt(128)
  }
  __syncthreads();

  // softmax per query row
  if (tid < 16) {
    const int i = tid;
    float m = -1e30f;
    for (int j = 0; j < nk; j++) m = fmaxf(m, sc[i][j]);
    float ssum = 0.f;
    for (int j = 0; j < nk; j++) {
      float e = __expf(sc[i][j] - m);
      sc[i][j] = e;
      ssum += e;
    }
    const float inv = 1.f / ssum;
    for (int j = 0; j < nk; j++) sc[i][j] *= inv;
  }
  __syncthreads();

  // PV: out[i][d] = sum_j p[i][j] * v[j][d]
  {
    const int i = tid >> 4, db = (tid & 15) * 8;
    float o[8];
#pragma unroll
    for (int u = 0; u < 8; u++) o[u] = 0.f;
    for (int j = 0; j < nk; j++) {
      const unsigned short* vp = (j == 0)
          ? (v + (size_t)frow * 1024 + fcol + db)
          : (v + (size_t)(kbase + (j - 1) * kstride) * 1024 + hcol + db);
      const float p = sc[i][j];
      uint4 r = *(const uint4*)vp;
      o[0] += p * b2f(r.x & 0xffffu); o[1] += p * b2f(r.x >> 16);
      o[2] += p * b2f(r.y & 0xffffu); o[3] += p * b2f(r.y >> 16);
      o[4] += p * b2f(r.z & 0xffffu); o[5] += p * b2f(r.z >> 16);
      o[6] += p * b2f(r.w & 0xffffu); o[7] += p * b2f(r.w >> 16);
    }
    if (i < nqv) {
      unsigned short* op = out + (size_t)(qbase + i * qstride) * 1024 + hcol + db;
      uint4 w;
      w.x = (unsigned)f2b(o[0]) | ((unsigned)f2b(o[1]) << 16);
      w.y = (unsigned)f2b(o[2]) | ((unsigned)f2b(o[3]) << 16);
      w.z = (unsigned)f2b(o[4]) | ((unsigned)f2b(o[5]) << 16);
      w.w = (unsigned)f2b(o[6]) | ((unsigned)f2b(o[7]) << 16);
      *(uint4*)op = w;
    }
  }
}

// ---------------- host ----------------
extern "C" void kernel_launch(void* const* d_in, const int* in_sizes, int n_in,
                              void* d_out, int out_size, void* d_ws, size_t ws_size,
                              hipStream_t stream) {
  const float* x        = (const float*)d_in[0];
  const float* W_in     = (const float*)d_in[1];
  const float* b_in     = (const float*)d_in[2];
  const float* g_in     = (const float*)d_in[3];
  const float* beta_in  = (const float*)d_in[4];
  const float* W_q      = (const float*)d_in[5];
  const float* W_k      = (const float*)d_in[6];
  const float* W_v      = (const float*)d_in[7];
  const float* g_out    = (const float*)d_in[8];
  const float* beta_out = (const float*)d_in[9];
  const float* W_out    = (const float*)d_in[10];
  const float* b_out    = (const float*)d_in[11];
  const int* att_type   = (const int*)d_in[12];
  float* out = (float*)d_out;

  char* ws = (char*)d_ws;
  const size_t MB = (size_t)M_P * 1024 * 2;   // 51,642,368 B per bf16 activation buffer
  unsigned short* xb = (unsigned short*)(ws + 0 * MB);  // x bf16 -> later attn out
  unsigned short* t1 = (unsigned short*)(ws + 1 * MB);  // gemm1 out -> later q
  unsigned short* xh = (unsigned short*)(ws + 2 * MB);  // ln1 out -> later ln2 out
  unsigned short* kb = (unsigned short*)(ws + 3 * MB);
  unsigned short* vb = (unsigned short*)(ws + 4 * MB);
  unsigned short* wt = (unsigned short*)(ws + 5 * MB);  // 5 transposed bf16 weights
  const size_t WSZ = (size_t)1024 * 1024;

  convert_pad<<<M_P, 256, 0, stream>>>(x, xb, M_R * 1024);

  WP wp;
  wp.s[0] = W_in; wp.s[1] = W_q; wp.s[2] = W_k; wp.s[3] = W_v; wp.s[4] = W_out;
  for (int i = 0; i < 5; i++) wp.d[i] = wt + (size_t)i * WSZ;
  transpose5<<<dim3(32, 32, 5), dim3(32, 8), 0, stream>>>(wp);

  dim3 ggrid(8, 197);
  // t1 = x @ W_in + b_in
  gemm_bt<1><<<ggrid, 256, 0, stream>>>(xb, wt + 0 * WSZ, b_in, t1, M_P);
  // xh = LN(t1)
  ln_kernel<<<M_P, 256, 0, stream>>>(t1, nullptr, g_in, beta_in, xh, M_R);
  // q := t1, k, v
  gemm_bt<0><<<ggrid, 256, 0, stream>>>(xh, wt + 1 * WSZ, nullptr, t1, M_P);
  gemm_bt<0><<<ggrid, 256, 0, stream>>>(xh, wt + 2 * WSZ, nullptr, kb, M_P);
  gemm_bt<0><<<ggrid, 256, 0, stream>>>(xh, wt + 3 * WSZ, nullptr, vb, M_P);
  // attention -> xb (rows l>=1); feat rows handled by ln2's src0 path
  attn_kernel<<<13312, 256, 0, stream>>>(t1, kb, vb, xb, att_type);
  // xh = LN2(concat(feat_q, seq))
  ln_kernel<<<M_P, 256, 0, stream>>>(xb, t1, g_out, beta_out, xh, M_R);
  // out = xh @ W_out + b_out (fp32, bounds-checked rows)
  gemm_bt<2><<<ggrid, 256, 0, stream>>>(xh, wt + 4 * WSZ, b_out, (void*)out, M_R);
}

// Round 2
// 689.016 us; speedup vs baseline: 1.1829x; 1.1829x over previous
//
#include <hip/hip_runtime.h>
#include <stdint.h>

// Problem constants
#define N_B 8
#define F_T 16
#define S_T 196
#define D_M 1024
#define H_N 8
#define HD  128
#define L_T 3137              // 1 + F*S
#define M_R (N_B * L_T)       // 25096 real rows
#define M_P 25216             // 197*128 padded rows

typedef __attribute__((ext_vector_type(8))) short bf16x8;
typedef __attribute__((ext_vector_type(4))) float f32x4;

__device__ __forceinline__ float b2f(unsigned int u) {
  union { unsigned int i; float f; } x; x.i = u << 16; return x.f;
}
__device__ __forceinline__ unsigned short f2b(float f) {
  union { float f; unsigned int i; } x; x.f = f;
  unsigned int r = x.i + 0x7fffu + ((x.i >> 16) & 1u);  // RNE
  return (unsigned short)(r >> 16);
}

// ---------------- convert fp32 x -> bf16, zero-pad rows M_R..M_P ----------------
__global__ __launch_bounds__(256) void convert_pad(const float* __restrict__ x,
                                                   unsigned short* __restrict__ xb,
                                                   int nreal) {
  int i = (blockIdx.x * 256 + threadIdx.x) * 4;
  float4 v;
  if (i < nreal) v = *(const float4*)(x + i);
  else { v.x = 0.f; v.y = 0.f; v.z = 0.f; v.w = 0.f; }
  ushort4 o;
  o.x = f2b(v.x); o.y = f2b(v.y); o.z = f2b(v.z); o.w = f2b(v.w);
  *(ushort4*)(xb + i) = o;
}

// ---------------- transpose 5 weights: W[k][n] fp32 -> Wt[n][k] bf16 ----------------
struct WP { const float* s[5]; unsigned short* d[5]; };
__global__ __launch_bounds__(256) void transpose5(WP p) {
  __shared__ float t[32][33];
  const int w = blockIdx.z;
  const float* W = p.s[w];
  unsigned short* Wt = p.d[w];
  const int tx = threadIdx.x, ty = threadIdx.y;    // 32 x 8
  const int n0 = blockIdx.x * 32, k0 = blockIdx.y * 32;
#pragma unroll
  for (int i = 0; i < 4; i++)
    t[ty + i * 8][tx] = W[(size_t)(k0 + ty + i * 8) * D_M + n0 + tx];
  __syncthreads();
#pragma unroll
  for (int i = 0; i < 4; i++)
    Wt[(size_t)(n0 + ty + i * 8) * D_M + k0 + tx] = f2b(t[tx][ty + i * 8]);
}

// ---------------- GEMM: C[M_P x 1024] = A[M_P x 1024] * Wt^T, m97-style ----------------
__device__ __forceinline__ void async16(const unsigned short* g, unsigned short* l) {
  __builtin_amdgcn_global_load_lds((const __attribute__((address_space(1))) void*)g,
                                   (__attribute__((address_space(3))) void*)l, 16, 0, 0);
}

// MODE 0: out bf16, no bias. MODE 1: out bf16 + bias. MODE 2: out fp32 + bias, row<Mreal guard.
template <int MODE>
__global__ __launch_bounds__(256) void gemm_bt(const unsigned short* __restrict__ A,
                                               const unsigned short* __restrict__ Bt,
                                               const float* __restrict__ bias,
                                               void* __restrict__ Cout, int Mreal) {
  __shared__ __align__(16) unsigned short As[128 * 32];  // [m][k], rows of 64B
  __shared__ __align__(16) unsigned short Bs[128 * 32];  // [n][k]
  const int tid = threadIdx.x;
  const int lane = tid & 63;
  const int wv = tid >> 6;
  const int wm = wv >> 1, wn = wv & 1;
  // XCD-aware swizzle: flat%8 ~ XCD id; give each XCD contiguous lin range so the
  // 8 col-blocks sharing an A row-tile land on the SAME XCD's L2. 1576 = 8*197.
  const int flat = blockIdx.y * 8 + blockIdx.x;
  const int lin = (flat & 7) * 197 + (flat >> 3);
  const int rowBase = (lin >> 3) * 128, colBase = (lin & 7) * 128;

  // staging: wave wv loads LDS chunks {2wv, 2wv+1} (1KB each) of A and B tiles
  const int c0 = 2 * wv, c1 = c0 + 1;
  const int srow = lane >> 2;           // row within 16-row chunk
  const int sk = (lane & 3) * 8;        // k element offset (16B granules)
  const unsigned short* gA0 = A + (size_t)(rowBase + c0 * 16 + srow) * 1024 + sk;
  const unsigned short* gA1 = A + (size_t)(rowBase + c1 * 16 + srow) * 1024 + sk;
  const unsigned short* gB0 = Bt + (size_t)(colBase + c0 * 16 + srow) * 1024 + sk;
  const unsigned short* gB1 = Bt + (size_t)(colBase + c1 * 16 + srow) * 1024 + sk;
  unsigned short* lA0 = As + c0 * 512;
  unsigned short* lA1 = As + c1 * 512;
  unsigned short* lB0 = Bs + c0 * 512;
  unsigned short* lB1 = Bs + c1 * 512;

  f32x4 acc[4][4] = {};

  // fragment read addresses: A[m=lane&15][k=(lane>>4)*8+j]
  const int mf = lane & 15, kg = lane >> 4;
  const unsigned short* Ar = As + (wm * 64 + mf) * 32 + kg * 8;
  const unsigned short* Br = Bs + (wn * 64 + mf) * 32 + kg * 8;

  for (int kt = 0; kt < 1024; kt += 32) {
    __syncthreads();                 // previous tile's ds_reads done
    async16(gA0 + kt, lA0);
    async16(gA1 + kt, lA1);
    async16(gB0 + kt, lB0);
    async16(gB1 + kt, lB1);
    __syncthreads();                 // drains vmcnt(0) -> LDS ready
    bf16x8 av[4], bv[4];
#pragma unroll
    for (int i = 0; i < 4; i++) av[i] = *(const bf16x8*)(Ar + i * 16 * 32);
#pragma unroll
    for (int j = 0; j < 4; j++) bv[j] = *(const bf16x8*)(Br + j * 16 * 32);
#pragma unroll
    for (int i = 0; i < 4; i++)
#pragma unroll
      for (int j = 0; j < 4; j++)
        acc[i][j] = __builtin_amdgcn_mfma_f32_16x16x32_bf16(av[i], bv[j], acc[i][j], 0, 0, 0);
  }

  // epilogue: C/D layout col=lane&15, row=(lane>>4)*4+reg
  const int r0 = (lane >> 4) * 4;
  const int cc = lane & 15;
#pragma unroll
  for (int j = 0; j < 4; j++) {
    const int col = colBase + wn * 64 + j * 16 + cc;
    const float bval = (MODE >= 1) ? bias[col] : 0.f;
#pragma unroll
    for (int i = 0; i < 4; i++) {
#pragma unroll
      for (int r = 0; r < 4; r++) {
        const int row = rowBase + wm * 64 + i * 16 + r0 + r;
        const float val = acc[i][j][r] + bval;
        if (MODE == 2) {
          if (row < Mreal) ((float*)Cout)[(size_t)row * 1024 + col] = val;
        } else {
          ((unsigned short*)Cout)[(size_t)row * 1024 + col] = f2b(val);
        }
      }
    }
  }
}

// ---------------- LayerNorm over rows of 1024, bf16 in/out ----------------
__global__ __launch_bounds__(256) void ln_kernel(const unsigned short* __restrict__ src,
                                                 const unsigned short* __restrict__ src0,
                                                 const float* __restrict__ g,
                                                 const float* __restrict__ beta,
                                                 unsigned short* __restrict__ out, int Mreal) {
  const int row = blockIdx.x, tid = threadIdx.x;
  unsigned short* op = out + (size_t)row * 1024 + tid * 4;
  if (row >= Mreal) {                       // zero the pad rows
    ushort4 z; z.x = 0; z.y = 0; z.z = 0; z.w = 0;
    *(ushort4*)op = z;
    return;
  }
  const unsigned short* s = src;
  if (src0 != nullptr && (row % L_T) == 0) s = src0;
  const unsigned short* ip = s + (size_t)row * 1024 + tid * 4;
  uint2 raw = *(const uint2*)ip;
  float x0 = b2f(raw.x & 0xffffu), x1 = b2f(raw.x >> 16);
  float x2 = b2f(raw.y & 0xffffu), x3 = b2f(raw.y >> 16);
  float sum = x0 + x1 + x2 + x3;
  float sq = x0 * x0 + x1 * x1 + x2 * x2 + x3 * x3;
#pragma unroll
  for (int off = 32; off > 0; off >>= 1) {
    sum += __shfl_down(sum, off);
    sq += __shfl_down(sq, off);
  }
  __shared__ float red[8];
  if ((tid & 63) == 0) { red[tid >> 6] = sum; red[4 + (tid >> 6)] = sq; }
  __syncthreads();
  const float ts = red[0] + red[1] + red[2] + red[3];
  const float tq = red[4] + red[5] + red[6] + red[7];
  const float mean = ts * (1.f / 1024.f);
  const float var = tq * (1.f / 1024.f) - mean * mean;
  const float rstd = rsqrtf(var + 1e-5f);
  const float4 gv = *(const float4*)(g + tid * 4);
  const float4 bv = *(const float4*)(beta + tid * 4);
  ushort4 o;
  o.x = f2b((x0 - mean) * rstd * gv.x + bv.x);
  o.y = f2b((x1 - mean) * rstd * gv.y + bv.y);
  o.z = f2b((x2 - mean) * rstd * gv.z + bv.z);
  o.w = f2b((x3 - mean) * rstd * gv.w + bv.w);
  *(ushort4*)op = o;
}

// ---------------- Attention ----------------
// type 1 (temporal, MFMA): 1 wave per s-problem (16 q x 17 k x 128d), 4 waves/block.
// type 0 (spatial, scalar fallback): block=(hb,f,qchunk), 16 q x 197 k.
// NOTE: jnp.tile(feat_k,(S,1,1)) means batch i uses feat head (i % 64), not its own head!
#define ATT_T_BLOCKS (64 * 49)    // 3136: hb x (196/4)
__global__ __launch_bounds__(256) void attn_kernel(const unsigned short* __restrict__ q,
                                                   const unsigned short* __restrict__ k,
                                                   const unsigned short* __restrict__ v,
                                                   unsigned short* __restrict__ out,
                                                   const int* __restrict__ att_type) {
  __shared__ __align__(16) char smem[22528];
  const int tid = threadIdx.x;
  const int bid = blockIdx.x;
  const int at = att_type[0];

  if (at == 1) {
    if (bid >= ATT_T_BLOCKS) return;
    const int lane = tid & 63, wv = tid >> 6;
    const int l15 = lane & 15, kg = lane >> 4;
    const int hb = bid / 49, sb = bid - hb * 49;
    const int s = sb * 4 + wv;                  // each wave owns one s
    const int n = hb >> 3, h = hb & 7;
    const int fi = (hb * S_T + s) & 63;         // tile() modular feat indexing
    const size_t frow = (size_t)(fi >> 3) * L_T;
    const int fcol = (fi & 7) * HD;
    const int qbase = n * L_T + 1 + s;
    const int hcol = h * HD;

    // wave-private LDS: P [16][32] bf16 (1KB) + V [17 keys][130 elem-stride] bf16
    unsigned short* Pl = (unsigned short*)(smem + wv * 5632);
    unsigned short* Vl = (unsigned short*)(smem + wv * 5632 + 1024);

    // ---- stage V rows coalesced into LDS (stride 130 -> conflict-free col reads)
    {
      const int dim0 = l15 * 8;
#pragma unroll
      for (int p = 0; p < 5; p++) {
        const int key = p * 4 + kg;
        if (key < 17) {
          const unsigned short* vp = (key == 0)
              ? (v + frow * 1024 + fcol + dim0)
              : (v + (size_t)(qbase + (key - 1) * S_T) * 1024 + hcol + dim0);
          uint4 r = *(const uint4*)vp;
          unsigned int* wp = (unsigned int*)Vl + key * 65 + l15 * 4;
          wp[0] = r.x; wp[1] = r.y; wp[2] = r.z; wp[3] = r.w;
        }
      }
    }

    // ---- Q fragments (A) and K fragments (B, natural layout) straight from global
    bf16x8 aq[4], bk0[4], bk1[4];
    {
      const unsigned short* qp = q + (size_t)(qbase + l15 * S_T) * 1024 + hcol + kg * 8;
      const unsigned short* kp = (l15 == 0)
          ? (k + frow * 1024 + fcol + kg * 8)                         // key 0 = feat
          : (k + (size_t)(qbase + (l15 - 1) * S_T) * 1024 + hcol + kg * 8);
      const unsigned short* kp1 = k + (size_t)(qbase + 15 * S_T) * 1024 + hcol + kg * 8;  // key 16
#pragma unroll
      for (int t = 0; t < 4; t++) {
        aq[t] = *(const bf16x8*)(qp + t * 32);
        bk0[t] = *(const bf16x8*)(kp + t * 32);
        if (l15 == 0) bk1[t] = *(const bf16x8*)(kp1 + t * 32);
        else {
          bf16x8 z = {};
          bk1[t] = z;
        }
      }
    }

    // ---- scores: c0 = keys 0..15, c1 col0 = key 16
    f32x4 c0 = {}, c1 = {};
#pragma unroll
    for (int t = 0; t < 4; t++) {
      c0 = __builtin_amdgcn_mfma_f32_16x16x32_bf16(aq[t], bk0[t], c0, 0, 0, 0);
      c1 = __builtin_amdgcn_mfma_f32_16x16x32_bf16(aq[t], bk1[t], c1, 0, 0, 0);
    }

    // ---- softmax in registers (16-lane butterflies), P -> LDS bf16
    const float scl = 0.08838834764831845f;   // 1/sqrt(128)
#pragma unroll
    for (int r = 0; r < 4; r++) {
      float v0 = c0[r] * scl;
      float k16 = __shfl(c1[r] * scl, lane & 48);   // col0 of this 16-lane group
      float mx = v0;
#pragma unroll
      for (int m = 1; m < 16; m <<= 1) mx = fmaxf(mx, __shfl_xor(mx, m));
      mx = fmaxf(mx, k16);
      float p = __expf(v0 - mx);
      float p16 = __expf(k16 - mx);
      float sum = p;
#pragma unroll
      for (int m = 1; m < 16; m <<= 1) sum += __shfl_xor(sum, m);
      sum += p16;
      const float inv = 1.f / sum;
      const int row = kg * 4 + r;                    // C layout: row=(lane>>4)*4+reg
      Pl[row * 32 + l15] = f2b(p * inv);
      Pl[row * 32 + 16 + l15] = (l15 == 0) ? f2b(p16 * inv) : (unsigned short)0;
    }

    // ---- PV: A = P (16x32, keys padded w/ 0), B = V^T gathered from LDS
    bf16x8 ap = *(const bf16x8*)(Pl + l15 * 32 + kg * 8);
#pragma unroll
    for (int nt = 0; nt < 8; nt++) {
      const int dim = nt * 16 + l15;
      bf16x8 bv;
#pragma unroll
      for (int j = 0; j < 8; j++) {
        const int key = kg * 8 + j;
        const int kc = (key < 17) ? key : 0;
        unsigned short raw = Vl[kc * 130 + dim];
        bv[j] = (key < 17) ? (short)raw : (short)0;
      }
      f32x4 z = {};
      f32x4 o = __builtin_amdgcn_mfma_f32_16x16x32_bf16(ap, bv, z, 0, 0, 0);
#pragma unroll
      for (int r = 0; r < 4; r++) {
        const int qi = kg * 4 + r;
        out[(size_t)(qbase + qi * S_T) * 1024 + hcol + nt * 16 + l15] = f2b(o[r]);
      }
    }
    return;
  }

  // ---------------- spatial fallback (scalar; not exercised when att_type==1) ----------------
  float (*qs)[132] = (float (*)[132])smem;                    // 16*132*4 = 8448 B
  float (*sc)[212] = (float (*)[212])(smem + 8448);           // 16*212*4 = 13568 B
  const int hb = bid / 208;
  const int rem = bid - hb * 208;
  const int f = rem / 13, qc = rem - f * 13;
  const int n = hb >> 3, h = hb & 7;
  const int fi = (hb * F_T + f) & 63;
  const size_t frow = (size_t)(fi >> 3) * L_T;
  const int fcol = (fi & 7) * HD;
  const int kbase = n * L_T + 1 + f * S_T;
  const int qbase = kbase + qc * 16;
  const int nk = S_T + 1;
  const int nqv = (qc == 12) ? 4 : 16;
  const int hcol = h * HD;

  {
    const int i = tid >> 4, db = (tid & 15) * 8;
    float* dst = &qs[i][db];
    if (i < nqv) {
      const unsigned short* qp = q + (size_t)(qbase + i) * 1024 + hcol + db;
      uint4 r = *(const uint4*)qp;
      dst[0] = b2f(r.x & 0xffffu); dst[1] = b2f(r.x >> 16);
      dst[2] = b2f(r.y & 0xffffu); dst[3] = b2f(r.y >> 16);
      dst[4] = b2f(r.z & 0xffffu); dst[5] = b2f(r.z >> 16);
      dst[6] = b2f(r.w & 0xffffu); dst[7] = b2f(r.w >> 16);
    } else {
#pragma unroll
      for (int u = 0; u < 8; u++) dst[u] = 0.f;
    }
  }
  __syncthreads();

  const int nslot = 16 * nk;
  for (int slot = tid; slot < nslot; slot += 256) {
    const int i = slot / nk, j = slot - i * nk;
    const unsigned short* kp = (j == 0)
        ? (k + frow * 1024 + fcol)
        : (k + (size_t)(kbase + (j - 1)) * 1024 + hcol);
    float acc = 0.f;
#pragma unroll 4
    for (int d = 0; d < 128; d += 8) {
      uint4 r = *(const uint4*)(kp + d);
      acc += qs[i][d + 0] * b2f(r.x & 0xffffu);
      acc += qs[i][d + 1] * b2f(r.x >> 16);
      acc += qs[i][d + 2] * b2f(r.y & 0xffffu);
      acc += qs[i][d + 3] * b2f(r.y >> 16);
      acc += qs[i][d + 4] * b2f(r.z & 0xffffu);
      acc += qs[i][d + 5] * b2f(r.z >> 16);
      acc += qs[i][d + 6] * b2f(r.w & 0xffffu);
      acc += qs[i][d + 7] * b2f(r.w >> 16);
    }
    sc[i][j] = acc * 0.08838834764831845f;
  }
  __syncthreads();

  if (tid < 16) {
    const int i = tid;
    float m = -1e30f;
    for (int j = 0; j < nk; j++) m = fmaxf(m, sc[i][j]);
    float ssum = 0.f;
    for (int j = 0; j < nk; j++) {
      float e = __expf(sc[i][j] - m);
      sc[i][j] = e;
      ssum += e;
    }
    const float inv = 1.f / ssum;
    for (int j = 0; j < nk; j++) sc[i][j] *= inv;
  }
  __syncthreads();

  {
    const int i = tid >> 4, db = (tid & 15) * 8;
    float o[8];
#pragma unroll
    for (int u = 0; u < 8; u++) o[u] = 0.f;
    for (int j = 0; j < nk; j++) {
      const unsigned short* vp = (j == 0)
          ? (v + frow * 1024 + fcol + db)
          : (v + (size_t)(kbase + (j - 1)) * 1024 + hcol + db);
      const float p = sc[i][j];
      uint4 r = *(const uint4*)vp;
      o[0] += p * b2f(r.x & 0xffffu); o[1] += p * b2f(r.x >> 16);
      o[2] += p * b2f(r.y & 0xffffu); o[3] += p * b2f(r.y >> 16);
      o[4] += p * b2f(r.z & 0xffffu); o[5] += p * b2f(r.z >> 16);
      o[6] += p * b2f(r.w & 0xffffu); o[7] += p * b2f(r.w >> 16);
    }
    if (i < nqv) {
      unsigned short* op = out + (size_t)(qbase + i) * 1024 + hcol + db;
      uint4 w;
      w.x = (unsigned)f2b(o[0]) | ((unsigned)f2b(o[1]) << 16);
      w.y = (unsigned)f2b(o[2]) | ((unsigned)f2b(o[3]) << 16);
      w.z = (unsigned)f2b(o[4]) | ((unsigned)f2b(o[5]) << 16);
      w.w = (unsigned)f2b(o[6]) | ((unsigned)f2b(o[7]) << 16);
      *(uint4*)op = w;
    }
  }
}

// ---------------- host ----------------
extern "C" void kernel_launch(void* const* d_in, const int* in_sizes, int n_in,
                              void* d_out, int out_size, void* d_ws, size_t ws_size,
                              hipStream_t stream) {
  const float* x        = (const float*)d_in[0];
  const float* W_in     = (const float*)d_in[1];
  const float* b_in     = (const float*)d_in[2];
  const float* g_in     = (const float*)d_in[3];
  const float* beta_in  = (const float*)d_in[4];
  const float* W_q      = (const float*)d_in[5];
  const float* W_k      = (const float*)d_in[6];
  const float* W_v      = (const float*)d_in[7];
  const float* g_out    = (const float*)d_in[8];
  const float* beta_out = (const float*)d_in[9];
  const float* W_out    = (const float*)d_in[10];
  const float* b_out    = (const float*)d_in[11];
  const int* att_type   = (const int*)d_in[12];
  float* out = (float*)d_out;

  char* ws = (char*)d_ws;
  const size_t MB = (size_t)M_P * 1024 * 2;   // bf16 activation buffer
  unsigned short* xb = (unsigned short*)(ws + 0 * MB);  // x bf16 -> later attn out
  unsigned short* t1 = (unsigned short*)(ws + 1 * MB);  // gemm1 out -> later q
  unsigned short* xh = (unsigned short*)(ws + 2 * MB);  // ln1 out -> later ln2 out
  unsigned short* kb = (unsigned short*)(ws + 3 * MB);
  unsigned short* vb = (unsigned short*)(ws + 4 * MB);
  unsigned short* wt = (unsigned short*)(ws + 5 * MB);  // 5 transposed bf16 weights
  const size_t WSZ = (size_t)1024 * 1024;

  convert_pad<<<M_P, 256, 0, stream>>>(x, xb, M_R * 1024);

  WP wp;
  wp.s[0] = W_in; wp.s[1] = W_q; wp.s[2] = W_k; wp.s[3] = W_v; wp.s[4] = W_out;
  for (int i = 0; i < 5; i++) wp.d[i] = wt + (size_t)i * WSZ;
  transpose5<<<dim3(32, 32, 5), dim3(32, 8), 0, stream>>>(wp);

  dim3 ggrid(8, 197);
  gemm_bt<1><<<ggrid, 256, 0, stream>>>(xb, wt + 0 * WSZ, b_in, t1, M_P);
  ln_kernel<<<M_P, 256, 0, stream>>>(t1, nullptr, g_in, beta_in, xh, M_R);
  gemm_bt<0><<<ggrid, 256, 0, stream>>>(xh, wt + 1 * WSZ, nullptr, t1, M_P);
  gemm_bt<0><<<ggrid, 256, 0, stream>>>(xh, wt + 2 * WSZ, nullptr, kb, M_P);
  gemm_bt<0><<<ggrid, 256, 0, stream>>>(xh, wt + 3 * WSZ, nullptr, vb, M_P);
  attn_kernel<<<13312, 256, 0, stream>>>(t1, kb, vb, xb, att_type);
  ln_kernel<<<M_P, 256, 0, stream>>>(xb, t1, g_out, beta_out, xh, M_R);
  gemm_bt<2><<<ggrid, 256, 0, stream>>>(xh, wt + 4 * WSZ, b_out, (void*)out, M_R);
}

// Round 3
// 637.942 us; speedup vs baseline: 1.2776x; 1.0801x over previous
//
#include <hip/hip_runtime.h>
#include <stdint.h>

// Problem constants
#define N_B 8
#define F_T 16
#define S_T 196
#define D_M 1024
#define H_N 8
#define HD  128
#define L_T 3137              // 1 + F*S
#define M_R (N_B * L_T)       // 25096 real rows
#define M_P 25216             // 197*128 padded rows

typedef __attribute__((ext_vector_type(8))) short bf16x8;
typedef __attribute__((ext_vector_type(4))) float f32x4;

__device__ __forceinline__ float b2f(unsigned int u) {
  union { unsigned int i; float f; } x; x.i = u << 16; return x.f;
}
__device__ __forceinline__ unsigned short f2b(float f) {
  union { float f; unsigned int i; } x; x.f = f;
  unsigned int r = x.i + 0x7fffu + ((x.i >> 16) & 1u);  // RNE
  return (unsigned short)(r >> 16);
}

// ---------------- convert fp32 x -> bf16, zero-pad rows M_R..M_P ----------------
__global__ __launch_bounds__(256) void convert_pad(const float* __restrict__ x,
                                                   unsigned short* __restrict__ xb,
                                                   int nreal) {
  int i = (blockIdx.x * 256 + threadIdx.x) * 4;
  float4 v;
  if (i < nreal) v = *(const float4*)(x + i);
  else { v.x = 0.f; v.y = 0.f; v.z = 0.f; v.w = 0.f; }
  ushort4 o;
  o.x = f2b(v.x); o.y = f2b(v.y); o.z = f2b(v.z); o.w = f2b(v.w);
  *(ushort4*)(xb + i) = o;
}

// ---------------- transpose 5 weights: W[k][n] fp32 -> Wt[n][k] bf16 ----------------
struct WP { const float* s[5]; unsigned short* d[5]; };
__global__ __launch_bounds__(256) void transpose5(WP p) {
  __shared__ float t[32][33];
  const int w = blockIdx.z;
  const float* W = p.s[w];
  unsigned short* Wt = p.d[w];
  const int tx = threadIdx.x, ty = threadIdx.y;    // 32 x 8
  const int n0 = blockIdx.x * 32, k0 = blockIdx.y * 32;
#pragma unroll
  for (int i = 0; i < 4; i++)
    t[ty + i * 8][tx] = W[(size_t)(k0 + ty + i * 8) * D_M + n0 + tx];
  __syncthreads();
#pragma unroll
  for (int i = 0; i < 4; i++)
    Wt[(size_t)(n0 + ty + i * 8) * D_M + k0 + tx] = f2b(t[tx][ty + i * 8]);
}

// ---------------- GEMM: m97-style + XOR-swizzled LDS + coalesced LDS epilogue ----------------
__device__ __forceinline__ void async16(const unsigned short* g, unsigned short* l) {
  __builtin_amdgcn_global_load_lds((const __attribute__((address_space(1))) void*)g,
                                   (__attribute__((address_space(3))) void*)l, 16, 0, 0);
}

struct Outs { void* p[3]; };

// MODE 1: bf16 out + bias (single out). MODE 2: fp32 out + bias, row guard. MODE 3: bf16, 3 outs (QKV), no bias.
template <int MODE>
__global__ __launch_bounds__(256) void gemm_bt(const unsigned short* __restrict__ A,
                                               const unsigned short* __restrict__ Bt,
                                               const float* __restrict__ bias,
                                               Outs o, int Mreal) {
  constexpr int NCB = (MODE == 3) ? 24 : 8;          // col-blocks
  __shared__ __align__(16) unsigned short lds[17408];  // 34816 B: As(8K)+Bs(8K) / C-stage
  unsigned short* As = lds;          // [128][32] u16, chunk-contiguous
  unsigned short* Bs = lds + 4096;
  const int tid = threadIdx.x;
  const int lane = tid & 63;
  const int wv = tid >> 6;
  const int wm = wv >> 1, wn = wv & 1;

  // XCD-aware swizzle: same-XCD blocks get contiguous lin -> shared A row-tiles in L2
  const int flat = blockIdx.y * NCB + blockIdx.x;
  int rowBase, colBase;
  if (MODE == 3) {
    const int lin = (flat & 7) * 591 + (flat >> 3);  // 4728 = 8*591
    rowBase = (lin / 24) * 128; colBase = (lin % 24) * 128;
  } else {
    const int lin = (flat & 7) * 197 + (flat >> 3);  // 1576 = 8*197
    rowBase = (lin >> 3) * 128; colBase = (lin & 7) * 128;
  }

  // staging: wave wv loads LDS chunks {2wv, 2wv+1} (16 rows x 32k each) of A and B.
  // XOR swizzle on the GLOBAL side: LDS[row][g] holds global granule g^(row&3).
  const int c0 = 2 * wv, c1 = c0 + 1;
  const int srow = lane >> 2;                // row within 16-row chunk
  const int sg = lane & 3;                   // LDS granule slot (16B)
  const int gk = ((sg ^ (srow & 3)) * 8);    // swizzled global k-offset (u16 elems)
  const unsigned short* gA0 = A + (size_t)(rowBase + c0 * 16 + srow) * 1024 + gk;
  const unsigned short* gA1 = A + (size_t)(rowBase + c1 * 16 + srow) * 1024 + gk;
  const unsigned short* gB0 = Bt + (size_t)(colBase + c0 * 16 + srow) * 1024 + gk;
  const unsigned short* gB1 = Bt + (size_t)(colBase + c1 * 16 + srow) * 1024 + gk;
  unsigned short* lA0 = As + c0 * 512;
  unsigned short* lA1 = As + c1 * 512;
  unsigned short* lB0 = Bs + c0 * 512;
  unsigned short* lB1 = Bs + c1 * 512;

  f32x4 acc[4][4] = {};

  // fragment reads: row=wm*64+i*16+mf, k-granule kg -> LDS slot kg^(mf&3)
  const int mf = lane & 15, kg = lane >> 4;
  const int slot = (kg ^ (mf & 3)) * 8;
  const unsigned short* Ar = As + (wm * 64 + mf) * 32 + slot;
  const unsigned short* Br = Bs + (wn * 64 + mf) * 32 + slot;

  for (int kt = 0; kt < 1024; kt += 32) {
    __syncthreads();                 // previous tile's ds_reads done
    async16(gA0 + kt, lA0);
    async16(gA1 + kt, lA1);
    async16(gB0 + kt, lB0);
    async16(gB1 + kt, lB1);
    __syncthreads();                 // drains vmcnt(0) -> LDS ready
    bf16x8 av[4], bv[4];
#pragma unroll
    for (int i = 0; i < 4; i++) av[i] = *(const bf16x8*)(Ar + i * 16 * 32);
#pragma unroll
    for (int j = 0; j < 4; j++) bv[j] = *(const bf16x8*)(Br + j * 16 * 32);
#pragma unroll
    for (int i = 0; i < 4; i++)
#pragma unroll
      for (int j = 0; j < 4; j++)
        acc[i][j] = __builtin_amdgcn_mfma_f32_16x16x32_bf16(av[i], bv[j], acc[i][j], 0, 0, 0);
  }

  // ---- epilogue: C/D layout col=lane&15, row=(lane>>4)*4+reg. Stage via LDS,
  // store coalesced 16B granules.
  __syncthreads();                   // last ds_reads done; lds is reusable
  if (MODE == 2) {
    float* Cf = (float*)lds;         // [64][132] fp32, two row-passes
    float* outF = (float*)o.p[0];
#pragma unroll
    for (int p = 0; p < 2; p++) {
      if (p) __syncthreads();
      if (wm == p) {
#pragma unroll
        for (int j = 0; j < 4; j++) {
          const int col_l = wn * 64 + j * 16 + mf;
          const float bval = bias[colBase + col_l];
#pragma unroll
          for (int i = 0; i < 4; i++)
#pragma unroll
            for (int r = 0; r < 4; r++)
              Cf[(i * 16 + kg * 4 + r) * 132 + col_l] = acc[i][j][r] + bval;
        }
      }
      __syncthreads();
      // store 64x128 fp32 = 2048 x 16B granules, 8 per thread
#pragma unroll
      for (int t = 0; t < 8; t++) {
        const int g = t * 256 + tid;
        const int row = g >> 5, ch = g & 31;
        const int grow = rowBase + p * 64 + row;
        if (grow < Mreal)
          *(float4*)(outF + (size_t)grow * 1024 + colBase + ch * 4) =
              *(const float4*)(Cf + row * 132 + ch * 4);
      }
    }
  } else {
    unsigned short* Cs = lds;        // [128][136] u16
#pragma unroll
    for (int j = 0; j < 4; j++) {
      const int col_l = wn * 64 + j * 16 + mf;
      const float bval = (MODE == 1) ? bias[colBase + col_l] : 0.f;
#pragma unroll
      for (int i = 0; i < 4; i++)
#pragma unroll
        for (int r = 0; r < 4; r++)
          Cs[(wm * 64 + i * 16 + kg * 4 + r) * 136 + col_l] = f2b(acc[i][j][r] + bval);
    }
    __syncthreads();
    unsigned short* C;
    int cb;
    if (MODE == 3) { C = (unsigned short*)o.p[colBase >> 10]; cb = colBase & 1023; }
    else { C = (unsigned short*)o.p[0]; cb = colBase; }
    // store 128x128 u16 = 2048 x 16B granules, 8 per thread
#pragma unroll
    for (int t = 0; t < 8; t++) {
      const int g = t * 256 + tid;
      const int row = g >> 4, ch = g & 15;
      *(uint4*)(C + (size_t)(rowBase + row) * 1024 + cb + ch * 8) =
          *(const uint4*)(Cs + row * 136 + ch * 8);
    }
  }
}

// ---------------- LayerNorm over rows of 1024, bf16 in/out ----------------
__global__ __launch_bounds__(256) void ln_kernel(const unsigned short* __restrict__ src,
                                                 const unsigned short* __restrict__ src0,
                                                 const float* __restrict__ g,
                                                 const float* __restrict__ beta,
                                                 unsigned short* __restrict__ out, int Mreal) {
  const int row = blockIdx.x, tid = threadIdx.x;
  unsigned short* op = out + (size_t)row * 1024 + tid * 4;
  if (row >= Mreal) {                       // zero the pad rows
    ushort4 z; z.x = 0; z.y = 0; z.z = 0; z.w = 0;
    *(ushort4*)op = z;
    return;
  }
  const unsigned short* s = src;
  if (src0 != nullptr && (row % L_T) == 0) s = src0;
  const unsigned short* ip = s + (size_t)row * 1024 + tid * 4;
  uint2 raw = *(const uint2*)ip;
  float x0 = b2f(raw.x & 0xffffu), x1 = b2f(raw.x >> 16);
  float x2 = b2f(raw.y & 0xffffu), x3 = b2f(raw.y >> 16);
  float sum = x0 + x1 + x2 + x3;
  float sq = x0 * x0 + x1 * x1 + x2 * x2 + x3 * x3;
#pragma unroll
  for (int off = 32; off > 0; off >>= 1) {
    sum += __shfl_down(sum, off);
    sq += __shfl_down(sq, off);
  }
  __shared__ float red[8];
  if ((tid & 63) == 0) { red[tid >> 6] = sum; red[4 + (tid >> 6)] = sq; }
  __syncthreads();
  const float ts = red[0] + red[1] + red[2] + red[3];
  const float tq = red[4] + red[5] + red[6] + red[7];
  const float mean = ts * (1.f / 1024.f);
  const float var = tq * (1.f / 1024.f) - mean * mean;
  const float rstd = rsqrtf(var + 1e-5f);
  const float4 gv = *(const float4*)(g + tid * 4);
  const float4 bv = *(const float4*)(beta + tid * 4);
  ushort4 o;
  o.x = f2b((x0 - mean) * rstd * gv.x + bv.x);
  o.y = f2b((x1 - mean) * rstd * gv.y + bv.y);
  o.z = f2b((x2 - mean) * rstd * gv.z + bv.z);
  o.w = f2b((x3 - mean) * rstd * gv.w + bv.w);
  *(ushort4*)op = o;
}

// ---------------- Attention ----------------
// type 1 (temporal, MFMA): 1 wave per s-problem (16 q x 17 k x 128d), 4 waves/block.
// type 0 (spatial, scalar fallback): block=(hb,f,qchunk), 16 q x 197 k.
// NOTE: jnp.tile(feat_k,(S,1,1)) means batch i uses feat head (i % 64), not its own head!
#define ATT_T_BLOCKS (64 * 49)    // 3136: hb x (196/4)
__global__ __launch_bounds__(256) void attn_kernel(const unsigned short* __restrict__ q,
                                                   const unsigned short* __restrict__ k,
                                                   const unsigned short* __restrict__ v,
                                                   unsigned short* __restrict__ out,
                                                   const int* __restrict__ att_type) {
  __shared__ __align__(16) char smem[22528];
  const int tid = threadIdx.x;
  const int bid = blockIdx.x;
  const int at = att_type[0];

  if (at == 1) {
    if (bid >= ATT_T_BLOCKS) return;
    const int lane = tid & 63, wv = tid >> 6;
    const int l15 = lane & 15, kg = lane >> 4;
    const int hb = bid / 49, sb = bid - hb * 49;
    const int s = sb * 4 + wv;                  // each wave owns one s
    const int n = hb >> 3, h = hb & 7;
    const int fi = (hb * S_T + s) & 63;         // tile() modular feat indexing
    const size_t frow = (size_t)(fi >> 3) * L_T;
    const int fcol = (fi & 7) * HD;
    const int qbase = n * L_T + 1 + s;
    const int hcol = h * HD;

    // wave-private LDS: P [16][32] bf16 (1KB) + V [17 keys][130 elem-stride] bf16
    unsigned short* Pl = (unsigned short*)(smem + wv * 5632);
    unsigned short* Vl = (unsigned short*)(smem + wv * 5632 + 1024);

    // ---- stage V rows coalesced into LDS (stride 130 -> conflict-free col reads)
    {
      const int dim0 = l15 * 8;
#pragma unroll
      for (int p = 0; p < 5; p++) {
        const int key = p * 4 + kg;
        if (key < 17) {
          const unsigned short* vp = (key == 0)
              ? (v + frow * 1024 + fcol + dim0)
              : (v + (size_t)(qbase + (key - 1) * S_T) * 1024 + hcol + dim0);
          uint4 r = *(const uint4*)vp;
          unsigned int* wp = (unsigned int*)Vl + key * 65 + l15 * 4;
          wp[0] = r.x; wp[1] = r.y; wp[2] = r.z; wp[3] = r.w;
        }
      }
    }

    // ---- Q fragments (A) and K fragments (B, natural layout) straight from global
    bf16x8 aq[4], bk0[4], bk1[4];
    {
      const unsigned short* qp = q + (size_t)(qbase + l15 * S_T) * 1024 + hcol + kg * 8;
      const unsigned short* kp = (l15 == 0)
          ? (k + frow * 1024 + fcol + kg * 8)                         // key 0 = feat
          : (k + (size_t)(qbase + (l15 - 1) * S_T) * 1024 + hcol + kg * 8);
      const unsigned short* kp1 = k + (size_t)(qbase + 15 * S_T) * 1024 + hcol + kg * 8;  // key 16
#pragma unroll
      for (int t = 0; t < 4; t++) {
        aq[t] = *(const bf16x8*)(qp + t * 32);
        bk0[t] = *(const bf16x8*)(kp + t * 32);
        if (l15 == 0) bk1[t] = *(const bf16x8*)(kp1 + t * 32);
        else {
          bf16x8 z = {};
          bk1[t] = z;
        }
      }
    }

    // ---- scores: c0 = keys 0..15, c1 col0 = key 16
    f32x4 c0 = {}, c1 = {};
#pragma unroll
    for (int t = 0; t < 4; t++) {
      c0 = __builtin_amdgcn_mfma_f32_16x16x32_bf16(aq[t], bk0[t], c0, 0, 0, 0);
      c1 = __builtin_amdgcn_mfma_f32_16x16x32_bf16(aq[t], bk1[t], c1, 0, 0, 0);
    }

    // ---- softmax in registers (16-lane butterflies), P -> LDS bf16
    const float scl = 0.08838834764831845f;   // 1/sqrt(128)
#pragma unroll
    for (int r = 0; r < 4; r++) {
      float v0 = c0[r] * scl;
      float k16 = __shfl(c1[r] * scl, lane & 48);   // col0 of this 16-lane group
      float mx = v0;
#pragma unroll
      for (int m = 1; m < 16; m <<= 1) mx = fmaxf(mx, __shfl_xor(mx, m));
      mx = fmaxf(mx, k16);
      float p = __expf(v0 - mx);
      float p16 = __expf(k16 - mx);
      float sum = p;
#pragma unroll
      for (int m = 1; m < 16; m <<= 1) sum += __shfl_xor(sum, m);
      sum += p16;
      const float inv = 1.f / sum;
      const int row = kg * 4 + r;                    // C layout: row=(lane>>4)*4+reg
      Pl[row * 32 + l15] = f2b(p * inv);
      Pl[row * 32 + 16 + l15] = (l15 == 0) ? f2b(p16 * inv) : (unsigned short)0;
    }

    // ---- PV: A = P (16x32, keys padded w/ 0), B = V^T gathered from LDS
    bf16x8 ap = *(const bf16x8*)(Pl + l15 * 32 + kg * 8);
#pragma unroll
    for (int nt = 0; nt < 8; nt++) {
      const int dim = nt * 16 + l15;
      bf16x8 bv;
#pragma unroll
      for (int j = 0; j < 8; j++) {
        const int key = kg * 8 + j;
        const int kc = (key < 17) ? key : 0;
        unsigned short raw = Vl[kc * 130 + dim];
        bv[j] = (key < 17) ? (short)raw : (short)0;
      }
      f32x4 z = {};
      f32x4 o = __builtin_amdgcn_mfma_f32_16x16x32_bf16(ap, bv, z, 0, 0, 0);
#pragma unroll
      for (int r = 0; r < 4; r++) {
        const int qi = kg * 4 + r;
        out[(size_t)(qbase + qi * S_T) * 1024 + hcol + nt * 16 + l15] = f2b(o[r]);
      }
    }
    return;
  }

  // ---------------- spatial fallback (scalar; not exercised when att_type==1) ----------------
  float (*qs)[132] = (float (*)[132])smem;                    // 16*132*4 = 8448 B
  float (*sc)[212] = (float (*)[212])(smem + 8448);           // 16*212*4 = 13568 B
  const int hb = bid / 208;
  const int rem = bid - hb * 208;
  const int f = rem / 13, qc = rem - f * 13;
  const int n = hb >> 3, h = hb & 7;
  const int fi = (hb * F_T + f) & 63;
  const size_t frow = (size_t)(fi >> 3) * L_T;
  const int fcol = (fi & 7) * HD;
  const int kbase = n * L_T + 1 + f * S_T;
  const int qbase = kbase + qc * 16;
  const int nk = S_T + 1;
  const int nqv = (qc == 12) ? 4 : 16;
  const int hcol = h * HD;

  {
    const int i = tid >> 4, db = (tid & 15) * 8;
    float* dst = &qs[i][db];
    if (i < nqv) {
      const unsigned short* qp = q + (size_t)(qbase + i) * 1024 + hcol + db;
      uint4 r = *(const uint4*)qp;
      dst[0] = b2f(r.x & 0xffffu); dst[1] = b2f(r.x >> 16);
      dst[2] = b2f(r.y & 0xffffu); dst[3] = b2f(r.y >> 16);
      dst[4] = b2f(r.z & 0xffffu); dst[5] = b2f(r.z >> 16);
      dst[6] = b2f(r.w & 0xffffu); dst[7] = b2f(r.w >> 16);
    } else {
#pragma unroll
      for (int u = 0; u < 8; u++) dst[u] = 0.f;
    }
  }
  __syncthreads();

  const int nslot = 16 * nk;
  for (int slot = tid; slot < nslot; slot += 256) {
    const int i = slot / nk, j = slot - i * nk;
    const unsigned short* kp = (j == 0)
        ? (k + frow * 1024 + fcol)
        : (k + (size_t)(kbase + (j - 1)) * 1024 + hcol);
    float acc = 0.f;
#pragma unroll 4
    for (int d = 0; d < 128; d += 8) {
      uint4 r = *(const uint4*)(kp + d);
      acc += qs[i][d + 0] * b2f(r.x & 0xffffu);
      acc += qs[i][d + 1] * b2f(r.x >> 16);
      acc += qs[i][d + 2] * b2f(r.y & 0xffffu);
      acc += qs[i][d + 3] * b2f(r.y >> 16);
      acc += qs[i][d + 4] * b2f(r.z & 0xffffu);
      acc += qs[i][d + 5] * b2f(r.z >> 16);
      acc += qs[i][d + 6] * b2f(r.w & 0xffffu);
      acc += qs[i][d + 7] * b2f(r.w >> 16);
    }
    sc[i][j] = acc * 0.08838834764831845f;
  }
  __syncthreads();

  if (tid < 16) {
    const int i = tid;
    float m = -1e30f;
    for (int j = 0; j < nk; j++) m = fmaxf(m, sc[i][j]);
    float ssum = 0.f;
    for (int j = 0; j < nk; j++) {
      float e = __expf(sc[i][j] - m);
      sc[i][j] = e;
      ssum += e;
    }
    const float inv = 1.f / ssum;
    for (int j = 0; j < nk; j++) sc[i][j] *= inv;
  }
  __syncthreads();

  {
    const int i = tid >> 4, db = (tid & 15) * 8;
    float o[8];
#pragma unroll
    for (int u = 0; u < 8; u++) o[u] = 0.f;
    for (int j = 0; j < nk; j++) {
      const unsigned short* vp = (j == 0)
          ? (v + frow * 1024 + fcol + db)
          : (v + (size_t)(kbase + (j - 1)) * 1024 + hcol + db);
      const float p = sc[i][j];
      uint4 r = *(const uint4*)vp;
      o[0] += p * b2f(r.x & 0xffffu); o[1] += p * b2f(r.x >> 16);
      o[2] += p * b2f(r.y & 0xffffu); o[3] += p * b2f(r.y >> 16);
      o[4] += p * b2f(r.z & 0xffffu); o[5] += p * b2f(r.z >> 16);
      o[6] += p * b2f(r.w & 0xffffu); o[7] += p * b2f(r.w >> 16);
    }
    if (i < nqv) {
      unsigned short* op = out + (size_t)(qbase + i) * 1024 + hcol + db;
      uint4 w;
      w.x = (unsigned)f2b(o[0]) | ((unsigned)f2b(o[1]) << 16);
      w.y = (unsigned)f2b(o[2]) | ((unsigned)f2b(o[3]) << 16);
      w.z = (unsigned)f2b(o[4]) | ((unsigned)f2b(o[5]) << 16);
      w.w = (unsigned)f2b(o[6]) | ((unsigned)f2b(o[7]) << 16);
      *(uint4*)op = w;
    }
  }
}

// ---------------- host ----------------
extern "C" void kernel_launch(void* const* d_in, const int* in_sizes, int n_in,
                              void* d_out, int out_size, void* d_ws, size_t ws_size,
                              hipStream_t stream) {
  const float* x        = (const float*)d_in[0];
  const float* W_in     = (const float*)d_in[1];
  const float* b_in     = (const float*)d_in[2];
  const float* g_in     = (const float*)d_in[3];
  const float* beta_in  = (const float*)d_in[4];
  const float* W_q      = (const float*)d_in[5];
  const float* W_k      = (const float*)d_in[6];
  const float* W_v      = (const float*)d_in[7];
  const float* g_out    = (const float*)d_in[8];
  const float* beta_out = (const float*)d_in[9];
  const float* W_out    = (const float*)d_in[10];
  const float* b_out    = (const float*)d_in[11];
  const int* att_type   = (const int*)d_in[12];
  float* out = (float*)d_out;

  char* ws = (char*)d_ws;
  const size_t MB = (size_t)M_P * 1024 * 2;   // bf16 activation buffer
  unsigned short* xb = (unsigned short*)(ws + 0 * MB);  // x bf16 -> later attn out
  unsigned short* t1 = (unsigned short*)(ws + 1 * MB);  // gemm1 out -> later q
  unsigned short* xh = (unsigned short*)(ws + 2 * MB);  // ln1 out -> later ln2 out
  unsigned short* kb = (unsigned short*)(ws + 3 * MB);
  unsigned short* vb = (unsigned short*)(ws + 4 * MB);
  unsigned short* wt = (unsigned short*)(ws + 5 * MB);  // transposed bf16 weights
  const size_t WSZ = (size_t)1024 * 1024;
  unsigned short* wt_in  = wt;                // W_in^T
  unsigned short* wqkv   = wt + 1 * WSZ;      // [3072][1024]: Wq^T | Wk^T | Wv^T
  unsigned short* wt_out = wt + 4 * WSZ;      // W_out^T

  convert_pad<<<M_P, 256, 0, stream>>>(x, xb, M_R * 1024);

  WP wp;
  wp.s[0] = W_in; wp.s[1] = W_q; wp.s[2] = W_k; wp.s[3] = W_v; wp.s[4] = W_out;
  wp.d[0] = wt_in;
  wp.d[1] = wqkv;
  wp.d[2] = wqkv + 1 * WSZ;
  wp.d[3] = wqkv + 2 * WSZ;
  wp.d[4] = wt_out;
  transpose5<<<dim3(32, 32, 5), dim3(32, 8), 0, stream>>>(wp);

  Outs o1; o1.p[0] = t1; o1.p[1] = nullptr; o1.p[2] = nullptr;
  gemm_bt<1><<<dim3(8, 197), 256, 0, stream>>>(xb, wt_in, b_in, o1, M_P);
  ln_kernel<<<M_P, 256, 0, stream>>>(t1, nullptr, g_in, beta_in, xh, M_R);

  Outs oq; oq.p[0] = t1; oq.p[1] = kb; oq.p[2] = vb;   // q -> t1
  gemm_bt<3><<<dim3(24, 197), 256, 0, stream>>>(xh, wqkv, nullptr, oq, M_P);

  attn_kernel<<<13312, 256, 0, stream>>>(t1, kb, vb, xb, att_type);
  ln_kernel<<<M_P, 256, 0, stream>>>(xb, t1, g_out, beta_out, xh, M_R);

  Outs oo; oo.p[0] = out; oo.p[1] = nullptr; oo.p[2] = nullptr;
  gemm_bt<2><<<dim3(8, 197), 256, 0, stream>>>(xh, wt_out, b_out, oo, M_R);
}

// Round 4
// 615.000 us; speedup vs baseline: 1.3253x; 1.0373x over previous
//
#include <hip/hip_runtime.h>
#include <stdint.h>

// Problem constants
#define N_B 8
#define F_T 16
#define S_T 196
#define D_M 1024
#define H_N 8
#define HD  128
#define L_T 3137              // 1 + F*S
#define M_R (N_B * L_T)       // 25096 real rows
#define M_P 25216             // 197*128 padded rows

typedef __attribute__((ext_vector_type(8))) short bf16x8;
typedef __attribute__((ext_vector_type(4))) float f32x4;

__device__ __forceinline__ float b2f(unsigned int u) {
  union { unsigned int i; float f; } x; x.i = u << 16; return x.f;
}
__device__ __forceinline__ unsigned short f2b(float f) {
  union { float f; unsigned int i; } x; x.f = f;
  unsigned int r = x.i + 0x7fffu + ((x.i >> 16) & 1u);  // RNE
  return (unsigned short)(r >> 16);
}

// ---------------- convert fp32 x -> bf16, zero-pad rows M_R..M_P ----------------
__global__ __launch_bounds__(256) void convert_pad(const float* __restrict__ x,
                                                   unsigned short* __restrict__ xb,
                                                   int nreal) {
  int i = (blockIdx.x * 256 + threadIdx.x) * 4;
  float4 v;
  if (i < nreal) v = *(const float4*)(x + i);
  else { v.x = 0.f; v.y = 0.f; v.z = 0.f; v.w = 0.f; }
  ushort4 o;
  o.x = f2b(v.x); o.y = f2b(v.y); o.z = f2b(v.z); o.w = f2b(v.w);
  *(ushort4*)(xb + i) = o;
}

// ---------------- transpose 5 weights: W[k][n] fp32 -> Wt[n][k] bf16 ----------------
struct WP { const float* s[5]; unsigned short* d[5]; };
__global__ __launch_bounds__(256) void transpose5(WP p) {
  __shared__ float t[32][33];
  const int w = blockIdx.z;
  const float* W = p.s[w];
  unsigned short* Wt = p.d[w];
  const int tx = threadIdx.x, ty = threadIdx.y;    // 32 x 8
  const int n0 = blockIdx.x * 32, k0 = blockIdx.y * 32;
#pragma unroll
  for (int i = 0; i < 4; i++)
    t[ty + i * 8][tx] = W[(size_t)(k0 + ty + i * 8) * D_M + n0 + tx];
  __syncthreads();
#pragma unroll
  for (int i = 0; i < 4; i++)
    Wt[(size_t)(n0 + ty + i * 8) * D_M + k0 + tx] = f2b(t[tx][ty + i * 8]);
}

// ---------------- GEMM: BK=64, XOR-8 swizzle, coalesced LDS epilogue ----------------
__device__ __forceinline__ void async16(const unsigned short* g, unsigned short* l) {
  __builtin_amdgcn_global_load_lds((const __attribute__((address_space(1))) void*)g,
                                   (__attribute__((address_space(3))) void*)l, 16, 0, 0);
}

struct Outs { void* p[3]; };

// MODE 1: bf16 out + bias. MODE 2: fp32 out + bias, row guard. MODE 3: bf16, 3 outs (QKV), no bias.
template <int MODE>
__global__ __launch_bounds__(256) void gemm_bt(const unsigned short* __restrict__ A,
                                               const unsigned short* __restrict__ Bt,
                                               const float* __restrict__ bias,
                                               Outs o, int Mreal) {
  constexpr int NCB = (MODE == 3) ? 24 : 8;          // col-blocks
  __shared__ __align__(16) unsigned short lds[17408];  // 34816 B: As(16K)+Bs(16K) / C-stage
  unsigned short* As = lds;          // [128][64] u16, 128B rows, granule-swizzled
  unsigned short* Bs = lds + 8192;
  const int tid = threadIdx.x;
  const int lane = tid & 63;
  const int wv = tid >> 6;
  const int wm = wv >> 1, wn = wv & 1;

  // Block ordering: XCD-contiguous lin; col-group-outer (8-col bands) so the live
  // B working set is 8 tiles = 2 MB (L2-resident); A streams once per band.
  const int flat = blockIdx.y * NCB + blockIdx.x;
  int rowBase, colBase;
  if (MODE == 3) {
    const int lin = (flat & 7) * 591 + (flat >> 3);  // 4728 = 8*591
    const int cg = lin / 1576;                       // 0..2 (col band of 8)
    const int rem = lin - cg * 1576;
    rowBase = (rem >> 3) * 128;
    colBase = (cg * 8 + (rem & 7)) * 128;
  } else {
    const int lin = (flat & 7) * 197 + (flat >> 3);  // 1576 = 8*197
    rowBase = (lin >> 3) * 128;
    colBase = (lin & 7) * 128;
  }

  // Staging (BK=64): each wave stages 4 chunks of 8 rows x 64k (1KB each) for A and B.
  // HW places lane at chunk_base + lane*16B = row (lane>>3), slot (lane&7).
  // XOR-8 swizzle on the GLOBAL side: slot s of row r holds global granule s^(r&7).
  const int srow8 = lane >> 3;               // row within 8-row chunk
  const int gk = ((lane & 7) ^ srow8) * 8;   // swizzled global k-offset (u16 elems)
  const unsigned short* gA = A + (size_t)(rowBase + wv * 32 + srow8) * 1024 + gk;
  const unsigned short* gB = Bt + (size_t)(colBase + wv * 32 + srow8) * 1024 + gk;
  unsigned short* lA = As + wv * 2048 + lane * 8;   // chunk ii adds 512 u16
  unsigned short* lB = Bs + wv * 2048 + lane * 8;

  f32x4 acc[4][4] = {};

  // Fragment reads: row = wm*64+i*16+mf (row&7 == mf&7), granule G = s2*4+kg,
  // LDS slot = G ^ (mf&7). Bank-enumeration: 8 lanes per 4-bank group -> conflict-free.
  const int mf = lane & 15, kg = lane >> 4;
  const int sl0 = ((kg) ^ (mf & 7)) * 8;
  const int sl1 = ((4 + kg) ^ (mf & 7)) * 8;
  const unsigned short* Ar = As + (wm * 64 + mf) * 64;
  const unsigned short* Br = Bs + (wn * 64 + mf) * 64;

  for (int kt = 0; kt < 1024; kt += 64) {
    __syncthreads();                 // previous tile's ds_reads done
#pragma unroll
    for (int ii = 0; ii < 4; ii++) {
      async16(gA + ii * 8 * 1024 + kt, lA + ii * 512);
      async16(gB + ii * 8 * 1024 + kt, lB + ii * 512);
    }
    __syncthreads();                 // drains vmcnt(0) -> LDS ready
    {
      bf16x8 av[4], bv[4];
#pragma unroll
      for (int i = 0; i < 4; i++) av[i] = *(const bf16x8*)(Ar + i * 1024 + sl0);
#pragma unroll
      for (int j = 0; j < 4; j++) bv[j] = *(const bf16x8*)(Br + j * 1024 + sl0);
#pragma unroll
      for (int i = 0; i < 4; i++)
#pragma unroll
        for (int j = 0; j < 4; j++)
          acc[i][j] = __builtin_amdgcn_mfma_f32_16x16x32_bf16(av[i], bv[j], acc[i][j], 0, 0, 0);
    }
    {
      bf16x8 av[4], bv[4];
#pragma unroll
      for (int i = 0; i < 4; i++) av[i] = *(const bf16x8*)(Ar + i * 1024 + sl1);
#pragma unroll
      for (int j = 0; j < 4; j++) bv[j] = *(const bf16x8*)(Br + j * 1024 + sl1);
#pragma unroll
      for (int i = 0; i < 4; i++)
#pragma unroll
        for (int j = 0; j < 4; j++)
          acc[i][j] = __builtin_amdgcn_mfma_f32_16x16x32_bf16(av[i], bv[j], acc[i][j], 0, 0, 0);
    }
  }

  // ---- epilogue: C/D layout col=lane&15, row=(lane>>4)*4+reg. Stage via LDS,
  // store coalesced 16B granules.
  __syncthreads();                   // last ds_reads done; lds is reusable
  if (MODE == 2) {
    float* Cf = (float*)lds;         // [64][132] fp32, two row-passes
    float* outF = (float*)o.p[0];
#pragma unroll
    for (int p = 0; p < 2; p++) {
      if (p) __syncthreads();
      if (wm == p) {
#pragma unroll
        for (int j = 0; j < 4; j++) {
          const int col_l = wn * 64 + j * 16 + mf;
          const float bval = bias[colBase + col_l];
#pragma unroll
          for (int i = 0; i < 4; i++)
#pragma unroll
            for (int r = 0; r < 4; r++)
              Cf[(i * 16 + kg * 4 + r) * 132 + col_l] = acc[i][j][r] + bval;
        }
      }
      __syncthreads();
      // store 64x128 fp32 = 2048 x 16B granules, 8 per thread
#pragma unroll
      for (int t = 0; t < 8; t++) {
        const int g = t * 256 + tid;
        const int row = g >> 5, ch = g & 31;
        const int grow = rowBase + p * 64 + row;
        if (grow < Mreal)
          *(float4*)(outF + (size_t)grow * 1024 + colBase + ch * 4) =
              *(const float4*)(Cf + row * 132 + ch * 4);
      }
    }
  } else {
    unsigned short* Cs = lds;        // [128][136] u16
#pragma unroll
    for (int j = 0; j < 4; j++) {
      const int col_l = wn * 64 + j * 16 + mf;
      const float bval = (MODE == 1) ? bias[colBase + col_l] : 0.f;
#pragma unroll
      for (int i = 0; i < 4; i++)
#pragma unroll
        for (int r = 0; r < 4; r++)
          Cs[(wm * 64 + i * 16 + kg * 4 + r) * 136 + col_l] = f2b(acc[i][j][r] + bval);
    }
    __syncthreads();
    unsigned short* C;
    int cb;
    if (MODE == 3) { C = (unsigned short*)o.p[colBase >> 10]; cb = colBase & 1023; }
    else { C = (unsigned short*)o.p[0]; cb = colBase; }
    // store 128x128 u16 = 2048 x 16B granules, 8 per thread
#pragma unroll
    for (int t = 0; t < 8; t++) {
      const int g = t * 256 + tid;
      const int row = g >> 4, ch = g & 15;
      *(uint4*)(C + (size_t)(rowBase + row) * 1024 + cb + ch * 8) =
          *(const uint4*)(Cs + row * 136 + ch * 8);
    }
  }
}

// ---------------- LayerNorm over rows of 1024, bf16 in/out ----------------
__global__ __launch_bounds__(256) void ln_kernel(const unsigned short* __restrict__ src,
                                                 const unsigned short* __restrict__ src0,
                                                 const float* __restrict__ g,
                                                 const float* __restrict__ beta,
                                                 unsigned short* __restrict__ out, int Mreal) {
  const int row = blockIdx.x, tid = threadIdx.x;
  unsigned short* op = out + (size_t)row * 1024 + tid * 4;
  if (row >= Mreal) {                       // zero the pad rows
    ushort4 z; z.x = 0; z.y = 0; z.z = 0; z.w = 0;
    *(ushort4*)op = z;
    return;
  }
  const unsigned short* s = src;
  if (src0 != nullptr && (row % L_T) == 0) s = src0;
  const unsigned short* ip = s + (size_t)row * 1024 + tid * 4;
  uint2 raw = *(const uint2*)ip;
  float x0 = b2f(raw.x & 0xffffu), x1 = b2f(raw.x >> 16);
  float x2 = b2f(raw.y & 0xffffu), x3 = b2f(raw.y >> 16);
  float sum = x0 + x1 + x2 + x3;
  float sq = x0 * x0 + x1 * x1 + x2 * x2 + x3 * x3;
#pragma unroll
  for (int off = 32; off > 0; off >>= 1) {
    sum += __shfl_down(sum, off);
    sq += __shfl_down(sq, off);
  }
  __shared__ float red[8];
  if ((tid & 63) == 0) { red[tid >> 6] = sum; red[4 + (tid >> 6)] = sq; }
  __syncthreads();
  const float ts = red[0] + red[1] + red[2] + red[3];
  const float tq = red[4] + red[5] + red[6] + red[7];
  const float mean = ts * (1.f / 1024.f);
  const float var = tq * (1.f / 1024.f) - mean * mean;
  const float rstd = rsqrtf(var + 1e-5f);
  const float4 gv = *(const float4*)(g + tid * 4);
  const float4 bv = *(const float4*)(beta + tid * 4);
  ushort4 o;
  o.x = f2b((x0 - mean) * rstd * gv.x + bv.x);
  o.y = f2b((x1 - mean) * rstd * gv.y + bv.y);
  o.z = f2b((x2 - mean) * rstd * gv.z + bv.z);
  o.w = f2b((x3 - mean) * rstd * gv.w + bv.w);
  *(ushort4*)op = o;
}

// ---------------- Attention ----------------
// type 1 (temporal, MFMA): 1 wave per s-problem (16 q x 17 k x 128d), 4 waves/block.
// type 0 (spatial, scalar fallback): block=(hb,f,qchunk), 16 q x 197 k.
// NOTE: jnp.tile(feat_k,(S,1,1)) means batch i uses feat head (i % 64), not its own head!
#define ATT_T_BLOCKS (64 * 49)    // 3136: hb x (196/4)
__global__ __launch_bounds__(256) void attn_kernel(const unsigned short* __restrict__ q,
                                                   const unsigned short* __restrict__ k,
                                                   const unsigned short* __restrict__ v,
                                                   unsigned short* __restrict__ out,
                                                   const int* __restrict__ att_type) {
  __shared__ __align__(16) char smem[22528];
  const int tid = threadIdx.x;
  const int bid = blockIdx.x;
  const int at = att_type[0];

  if (at == 1) {
    if (bid >= ATT_T_BLOCKS) return;
    const int lane = tid & 63, wv = tid >> 6;
    const int l15 = lane & 15, kg = lane >> 4;
    const int hb = bid / 49, sb = bid - hb * 49;
    const int s = sb * 4 + wv;                  // each wave owns one s
    const int n = hb >> 3, h = hb & 7;
    const int fi = (hb * S_T + s) & 63;         // tile() modular feat indexing
    const size_t frow = (size_t)(fi >> 3) * L_T;
    const int fcol = (fi & 7) * HD;
    const int qbase = n * L_T + 1 + s;
    const int hcol = h * HD;

    // wave-private LDS: P [16][32] bf16 (1KB) + V [17 keys][130 elem-stride] bf16
    unsigned short* Pl = (unsigned short*)(smem + wv * 5632);
    unsigned short* Vl = (unsigned short*)(smem + wv * 5632 + 1024);

    // ---- stage V rows coalesced into LDS (stride 130 -> conflict-free col reads)
    {
      const int dim0 = l15 * 8;
#pragma unroll
      for (int p = 0; p < 5; p++) {
        const int key = p * 4 + kg;
        if (key < 17) {
          const unsigned short* vp = (key == 0)
              ? (v + frow * 1024 + fcol + dim0)
              : (v + (size_t)(qbase + (key - 1) * S_T) * 1024 + hcol + dim0);
          uint4 r = *(const uint4*)vp;
          unsigned int* wp = (unsigned int*)Vl + key * 65 + l15 * 4;
          wp[0] = r.x; wp[1] = r.y; wp[2] = r.z; wp[3] = r.w;
        }
      }
    }

    // ---- Q fragments (A) and K fragments (B, natural layout) straight from global
    bf16x8 aq[4], bk0[4], bk1[4];
    {
      const unsigned short* qp = q + (size_t)(qbase + l15 * S_T) * 1024 + hcol + kg * 8;
      const unsigned short* kp = (l15 == 0)
          ? (k + frow * 1024 + fcol + kg * 8)                         // key 0 = feat
          : (k + (size_t)(qbase + (l15 - 1) * S_T) * 1024 + hcol + kg * 8);
      const unsigned short* kp1 = k + (size_t)(qbase + 15 * S_T) * 1024 + hcol + kg * 8;  // key 16
#pragma unroll
      for (int t = 0; t < 4; t++) {
        aq[t] = *(const bf16x8*)(qp + t * 32);
        bk0[t] = *(const bf16x8*)(kp + t * 32);
        if (l15 == 0) bk1[t] = *(const bf16x8*)(kp1 + t * 32);
        else {
          bf16x8 z = {};
          bk1[t] = z;
        }
      }
    }

    // ---- scores: c0 = keys 0..15, c1 col0 = key 16
    f32x4 c0 = {}, c1 = {};
#pragma unroll
    for (int t = 0; t < 4; t++) {
      c0 = __builtin_amdgcn_mfma_f32_16x16x32_bf16(aq[t], bk0[t], c0, 0, 0, 0);
      c1 = __builtin_amdgcn_mfma_f32_16x16x32_bf16(aq[t], bk1[t], c1, 0, 0, 0);
    }

    // ---- softmax in registers (16-lane butterflies), P -> LDS bf16
    const float scl = 0.08838834764831845f;   // 1/sqrt(128)
#pragma unroll
    for (int r = 0; r < 4; r++) {
      float v0 = c0[r] * scl;
      float k16 = __shfl(c1[r] * scl, lane & 48);   // col0 of this 16-lane group
      float mx = v0;
#pragma unroll
      for (int m = 1; m < 16; m <<= 1) mx = fmaxf(mx, __shfl_xor(mx, m));
      mx = fmaxf(mx, k16);
      float p = __expf(v0 - mx);
      float p16 = __expf(k16 - mx);
      float sum = p;
#pragma unroll
      for (int m = 1; m < 16; m <<= 1) sum += __shfl_xor(sum, m);
      sum += p16;
      const float inv = 1.f / sum;
      const int row = kg * 4 + r;                    // C layout: row=(lane>>4)*4+reg
      Pl[row * 32 + l15] = f2b(p * inv);
      Pl[row * 32 + 16 + l15] = (l15 == 0) ? f2b(p16 * inv) : (unsigned short)0;
    }

    // ---- PV: A = P (16x32, keys padded w/ 0), B = V^T gathered from LDS
    bf16x8 ap = *(const bf16x8*)(Pl + l15 * 32 + kg * 8);
#pragma unroll
    for (int nt = 0; nt < 8; nt++) {
      const int dim = nt * 16 + l15;
      bf16x8 bv;
#pragma unroll
      for (int j = 0; j < 8; j++) {
        const int key = kg * 8 + j;
        const int kc = (key < 17) ? key : 0;
        unsigned short raw = Vl[kc * 130 + dim];
        bv[j] = (key < 17) ? (short)raw : (short)0;
      }
      f32x4 z = {};
      f32x4 o = __builtin_amdgcn_mfma_f32_16x16x32_bf16(ap, bv, z, 0, 0, 0);
#pragma unroll
      for (int r = 0; r < 4; r++) {
        const int qi = kg * 4 + r;
        out[(size_t)(qbase + qi * S_T) * 1024 + hcol + nt * 16 + l15] = f2b(o[r]);
      }
    }
    return;
  }

  // ---------------- spatial fallback (scalar; not exercised when att_type==1) ----------------
  float (*qs)[132] = (float (*)[132])smem;                    // 16*132*4 = 8448 B
  float (*sc)[212] = (float (*)[212])(smem + 8448);           // 16*212*4 = 13568 B
  const int hb = bid / 208;
  const int rem = bid - hb * 208;
  const int f = rem / 13, qc = rem - f * 13;
  const int n = hb >> 3, h = hb & 7;
  const int fi = (hb * F_T + f) & 63;
  const size_t frow = (size_t)(fi >> 3) * L_T;
  const int fcol = (fi & 7) * HD;
  const int kbase = n * L_T + 1 + f * S_T;
  const int qbase = kbase + qc * 16;
  const int nk = S_T + 1;
  const int nqv = (qc == 12) ? 4 : 16;
  const int hcol = h * HD;

  {
    const int i = tid >> 4, db = (tid & 15) * 8;
    float* dst = &qs[i][db];
    if (i < nqv) {
      const unsigned short* qp = q + (size_t)(qbase + i) * 1024 + hcol + db;
      uint4 r = *(const uint4*)qp;
      dst[0] = b2f(r.x & 0xffffu); dst[1] = b2f(r.x >> 16);
      dst[2] = b2f(r.y & 0xffffu); dst[3] = b2f(r.y >> 16);
      dst[4] = b2f(r.z & 0xffffu); dst[5] = b2f(r.z >> 16);
      dst[6] = b2f(r.w & 0xffffu); dst[7] = b2f(r.w >> 16);
    } else {
#pragma unroll
      for (int u = 0; u < 8; u++) dst[u] = 0.f;
    }
  }
  __syncthreads();

  const int nslot = 16 * nk;
  for (int slot = tid; slot < nslot; slot += 256) {
    const int i = slot / nk, j = slot - i * nk;
    const unsigned short* kp = (j == 0)
        ? (k + frow * 1024 + fcol)
        : (k + (size_t)(kbase + (j - 1)) * 1024 + hcol);
    float acc = 0.f;
#pragma unroll 4
    for (int d = 0; d < 128; d += 8) {
      uint4 r = *(const uint4*)(kp + d);
      acc += qs[i][d + 0] * b2f(r.x & 0xffffu);
      acc += qs[i][d + 1] * b2f(r.x >> 16);
      acc += qs[i][d + 2] * b2f(r.y & 0xffffu);
      acc += qs[i][d + 3] * b2f(r.y >> 16);
      acc += qs[i][d + 4] * b2f(r.z & 0xffffu);
      acc += qs[i][d + 5] * b2f(r.z >> 16);
      acc += qs[i][d + 6] * b2f(r.w & 0xffffu);
      acc += qs[i][d + 7] * b2f(r.w >> 16);
    }
    sc[i][j] = acc * 0.08838834764831845f;
  }
  __syncthreads();

  if (tid < 16) {
    const int i = tid;
    float m = -1e30f;
    for (int j = 0; j < nk; j++) m = fmaxf(m, sc[i][j]);
    float ssum = 0.f;
    for (int j = 0; j < nk; j++) {
      float e = __expf(sc[i][j] - m);
      sc[i][j] = e;
      ssum += e;
    }
    const float inv = 1.f / ssum;
    for (int j = 0; j < nk; j++) sc[i][j] *= inv;
  }
  __syncthreads();

  {
    const int i = tid >> 4, db = (tid & 15) * 8;
    float o[8];
#pragma unroll
    for (int u = 0; u < 8; u++) o[u] = 0.f;
    for (int j = 0; j < nk; j++) {
      const unsigned short* vp = (j == 0)
          ? (v + frow * 1024 + fcol + db)
          : (v + (size_t)(kbase + (j - 1)) * 1024 + hcol + db);
      const float p = sc[i][j];
      uint4 r = *(const uint4*)vp;
      o[0] += p * b2f(r.x & 0xffffu); o[1] += p * b2f(r.x >> 16);
      o[2] += p * b2f(r.y & 0xffffu); o[3] += p * b2f(r.y >> 16);
      o[4] += p * b2f(r.z & 0xffffu); o[5] += p * b2f(r.z >> 16);
      o[6] += p * b2f(r.w & 0xffffu); o[7] += p * b2f(r.w >> 16);
    }
    if (i < nqv) {
      unsigned short* op = out + (size_t)(qbase + i) * 1024 + hcol + db;
      uint4 w;
      w.x = (unsigned)f2b(o[0]) | ((unsigned)f2b(o[1]) << 16);
      w.y = (unsigned)f2b(o[2]) | ((unsigned)f2b(o[3]) << 16);
      w.z = (unsigned)f2b(o[4]) | ((unsigned)f2b(o[5]) << 16);
      w.w = (unsigned)f2b(o[6]) | ((unsigned)f2b(o[7]) << 16);
      *(uint4*)op = w;
    }
  }
}

// ---------------- host ----------------
extern "C" void kernel_launch(void* const* d_in, const int* in_sizes, int n_in,
                              void* d_out, int out_size, void* d_ws, size_t ws_size,
                              hipStream_t stream) {
  const float* x        = (const float*)d_in[0];
  const float* W_in     = (const float*)d_in[1];
  const float* b_in     = (const float*)d_in[2];
  const float* g_in     = (const float*)d_in[3];
  const float* beta_in  = (const float*)d_in[4];
  const float* W_q      = (const float*)d_in[5];
  const float* W_k      = (const float*)d_in[6];
  const float* W_v      = (const float*)d_in[7];
  const float* g_out    = (const float*)d_in[8];
  const float* beta_out = (const float*)d_in[9];
  const float* W_out    = (const float*)d_in[10];
  const float* b_out    = (const float*)d_in[11];
  const int* att_type   = (const int*)d_in[12];
  float* out = (float*)d_out;

  char* ws = (char*)d_ws;
  const size_t MB = (size_t)M_P * 1024 * 2;   // bf16 activation buffer
  unsigned short* xb = (unsigned short*)(ws + 0 * MB);  // x bf16 -> later attn out
  unsigned short* t1 = (unsigned short*)(ws + 1 * MB);  // gemm1 out -> later q
  unsigned short* xh = (unsigned short*)(ws + 2 * MB);  // ln1 out -> later ln2 out
  unsigned short* kb = (unsigned short*)(ws + 3 * MB);
  unsigned short* vb = (unsigned short*)(ws + 4 * MB);
  unsigned short* wt = (unsigned short*)(ws + 5 * MB);  // transposed bf16 weights
  const size_t WSZ = (size_t)1024 * 1024;
  unsigned short* wt_in  = wt;                // W_in^T
  unsigned short* wqkv   = wt + 1 * WSZ;      // [3072][1024]: Wq^T | Wk^T | Wv^T
  unsigned short* wt_out = wt + 4 * WSZ;      // W_out^T

  convert_pad<<<M_P, 256, 0, stream>>>(x, xb, M_R * 1024);

  WP wp;
  wp.s[0] = W_in; wp.s[1] = W_q; wp.s[2] = W_k; wp.s[3] = W_v; wp.s[4] = W_out;
  wp.d[0] = wt_in;
  wp.d[1] = wqkv;
  wp.d[2] = wqkv + 1 * WSZ;
  wp.d[3] = wqkv + 2 * WSZ;
  wp.d[4] = wt_out;
  transpose5<<<dim3(32, 32, 5), dim3(32, 8), 0, stream>>>(wp);

  Outs o1; o1.p[0] = t1; o1.p[1] = nullptr; o1.p[2] = nullptr;
  gemm_bt<1><<<dim3(8, 197), 256, 0, stream>>>(xb, wt_in, b_in, o1, M_P);
  ln_kernel<<<M_P, 256, 0, stream>>>(t1, nullptr, g_in, beta_in, xh, M_R);

  Outs oq; oq.p[0] = t1; oq.p[1] = kb; oq.p[2] = vb;   // q -> t1
  gemm_bt<3><<<dim3(24, 197), 256, 0, stream>>>(xh, wqkv, nullptr, oq, M_P);

  attn_kernel<<<13312, 256, 0, stream>>>(t1, kb, vb, xb, att_type);
  ln_kernel<<<M_P, 256, 0, stream>>>(xb, t1, g_out, beta_out, xh, M_R);

  Outs oo; oo.p[0] = out; oo.p[1] = nullptr; oo.p[2] = nullptr;
  gemm_bt<2><<<dim3(8, 197), 256, 0, stream>>>(xh, wt_out, b_out, oo, M_R);
}